// Round 5
// baseline (883.361 us; speedup 1.0000x reference)
//
#include <hip/hip_runtime.h>

typedef float f32x4 __attribute__((ext_vector_type(4)));
typedef _Float16 f16x8 __attribute__((ext_vector_type(8)));
typedef _Float16 f16x4 __attribute__((ext_vector_type(4)));
typedef _Float16 f16x2 __attribute__((ext_vector_type(2)));

#define NB 256
#define NL 256
#define NIN 256
#define ND 128
#define NH 64
#define CH 16                        // X-chunk (steps)

// raw barrier: LDS-only drain — global ops float across it
#define BAR_LDS() asm volatile("s_waitcnt lgkmcnt(0)\n\ts_barrier" ::: "memory")

// =====================================================================
// Kernel W: pack w_r|w_z|w_h (f32 [128][256]) into f16 fragment order.
// wpk[((nt*8+kc)*64+lane)*8+j] = w_gate[(nt&7)*16+(lane&15)]
//                                 [kc*32+(lane>>4)*8+j];  192 KB, L2-hot.
// =====================================================================
__global__ void kwpack_kernel(const float* __restrict__ w_r,
                              const float* __restrict__ w_z,
                              const float* __restrict__ w_h,
                              _Float16* __restrict__ wpk) {
  const int lane = threadIdx.x;        // 0..63
  const int nt = blockIdx.x;           // 0..23
  const int kc = blockIdx.y;           // 0..7
  const float* wg = (nt < 8) ? w_r : (nt < 16) ? w_z : w_h;
  const int col = (nt & 7) * 16 + (lane & 15);
  const int k0 = kc * 32 + (lane >> 4) * 8;
  const float4* p = (const float4*)(wg + (size_t)col * NIN + k0);
  float4 v0 = p[0], v1 = p[1];
  f16x8 f;
  f[0] = (_Float16)v0.x; f[1] = (_Float16)v0.y;
  f[2] = (_Float16)v0.z; f[3] = (_Float16)v0.w;
  f[4] = (_Float16)v1.x; f[5] = (_Float16)v1.y;
  f[6] = (_Float16)v1.z; f[7] = (_Float16)v1.w;
  *(f16x8*)&wpk[(((size_t)nt * 8 + kc) * 64 + lane) * 8] = f;
}

// =====================================================================
// Kernel C v12: 16-wave fused scan (1024 threads, 4 waves/SIMD).
//  - waves 0..7: scan, schedule byte-identical to v11 (R4, 179us):
//    8-way d-split, accL/accH raw MFMAs, f32 combine in owner epilogue,
//    one BAR_LDS per step. gload staging + WAIT_VM0 DELETED.
//  - waves 8..15: dedicated projection waves. Chunk-ahead pipeline,
//    sliced across tins so each step's slice is small:
//      tin0: load next chunk's x rows (2 rows/wave, f32)   [global]
//      tin2: cvt -> Axt + a=sigmoid(x.k12) shfl-reduce -> sA
//      tin3-6: staggered LOADB (wpk, L2-hot) + 8-MFMA GEMM per n-tile
//              -> write Xl[buf^1] (straight [g][tin][d] layout)
//    Proj work overlaps the scan chain on separate waves; the shared
//    per-step barrier gives cross-wave visibility (write tin<=6,
//    read next chunk).
//  - kproj + wsX (48MB HBM round-trip) eliminated.
// =====================================================================
__global__ __launch_bounds__(1024) void kscan_kernel(
    const float* __restrict__ u_r, const float* __restrict__ u_z,
    const float* __restrict__ u_h, const float* __restrict__ b_r,
    const float* __restrict__ b_z, const float* __restrict__ b_h,
    const int* __restrict__ cor, const float* __restrict__ x,
    const _Float16* __restrict__ wpk, const float* __restrict__ k1k2,
    float* __restrict__ out) {
  const int b = blockIdx.x;
  const int tid = threadIdx.x;
  const int lane = tid & 63;
  const int w = tid >> 6;        // 0..15
  const bool scanw = (w < 8);    // waves 0..7 scan, 8..15 projection
  const int pw = w - 8;          // proj wave id 0..7
  const int quad = lane >> 4;
  const int l16 = lane & 15;
  const int q8 = quad * 8;

  __shared__ __align__(16) _Float16 hist[(NL + 1) * NH];   // 32896 B
  __shared__ __align__(16) _Float16 Xl[2 * 3 * CH * ND];   // 24576 B
  __shared__ __align__(16) _Float16 Axt[16 * 264];         // 8448 B (pad 264)
  __shared__ __align__(16) _Float16 hprev16[2][NH];        // 256 B (parity)
  __shared__ float sA[NL];                                 // 1024 B
  __shared__ int sIeff[NL];                                // 1024 B
  __shared__ float k12[NIN];                               // 1024 B

  const size_t rowb = (size_t)b * NL;

  // ---- scan waves: U fragments; n = 16w+l16, k = kk*32+q8+j ----
  f16x8 bf[3][4];
  if (scanw) {
#pragma unroll
    for (int g = 0; g < 3; ++g) {
      const float* ug = (g == 0) ? u_r : (g == 1) ? u_z : u_h;
      const float* base = ug + (size_t)(16 * w + l16) * ND;
#pragma unroll
      for (int kk = 0; kk < 4; ++kk) {
        const float4* p = (const float4*)(base + kk * 32 + q8);
        float4 v0 = p[0], v1 = p[1];
        f16x8 f;
        f[0] = (_Float16)v0.x; f[1] = (_Float16)v0.y;
        f[2] = (_Float16)v0.z; f[3] = (_Float16)v0.w;
        f[4] = (_Float16)v1.x; f[5] = (_Float16)v1.y;
        f[6] = (_Float16)v1.z; f[7] = (_Float16)v1.w;
        bf[g][kk] = f;
      }
    }
  }

  if (tid < NH) { hprev16[0][tid] = (_Float16)0.f; hist[tid] = (_Float16)0.f; }
  if (tid < NL) {
    const int c = cor[rowb + tid];
    sIeff[tid] = (c == 0) ? tid : c;
  }
  if (tid < NIN) k12[tid] = k1k2[tid] - k1k2[NIN + tid];

  // ---- proj-wave machinery ----
  const int prow0 = 2 * pw;            // chunk-local rows this wave stages
  float4 xrA0, xrA1, xrB0, xrB1;       // staged x (row0: A0/A1, row1: B0/B1)
  f16x8 bfr[8];                        // W-frags for one n-tile

  auto LOADX = [&](int t0) {
    const float4* pa = (const float4*)(x + (rowb + t0 + prow0) * NIN + lane * 4);
    const float4* pb = (const float4*)(x + (rowb + t0 + prow0 + 1) * NIN + lane * 4);
    xrA0 = pa[0];
    xrB0 = pb[0];
    // lane*4 covers 256 cols with 64 lanes exactly -> one float4 per row
    (void)xrA1; (void)xrB1;
  };
  auto STAGEX = [&](int t0) {
    f16x4 ha, hb;
    ha[0] = (_Float16)xrA0.x; ha[1] = (_Float16)xrA0.y;
    ha[2] = (_Float16)xrA0.z; ha[3] = (_Float16)xrA0.w;
    hb[0] = (_Float16)xrB0.x; hb[1] = (_Float16)xrB0.y;
    hb[2] = (_Float16)xrB0.z; hb[3] = (_Float16)xrB0.w;
    *(f16x4*)&Axt[prow0 * 264 + lane * 4] = ha;
    *(f16x4*)&Axt[(prow0 + 1) * 264 + lane * 4] = hb;
    const float4 kk = *(const float4*)&k12[lane * 4];
    float pa = xrA0.x * kk.x + xrA0.y * kk.y + xrA0.z * kk.z + xrA0.w * kk.w;
    float pb = xrB0.x * kk.x + xrB0.y * kk.y + xrB0.z * kk.z + xrB0.w * kk.w;
#pragma unroll
    for (int s = 1; s < 64; s <<= 1) {
      pa += __shfl_xor(pa, s);
      pb += __shfl_xor(pb, s);
    }
    if (lane == 0) {
      sA[t0 + prow0] = 1.f / (1.f + __expf(-pa));
      sA[t0 + prow0 + 1] = 1.f / (1.f + __expf(-pb));
    }
  };
  auto LOADB = [&](int i) {
    const int nt = pw * 3 + i;
#pragma unroll
    for (int kk = 0; kk < 8; ++kk)
      bfr[kk] = *(const f16x8*)&wpk[(((size_t)nt * 8 + kk) * 64 + lane) * 8];
  };
  auto GEMMG = [&](int i, int buf) {
    const int nt = pw * 3 + i;
    const int g = nt >> 3;
    const int dblk = nt & 7;
    f32x4 accP = (f32x4){0.f, 0.f, 0.f, 0.f};
#pragma unroll
    for (int kk = 0; kk < 8; ++kk) {
      f16x8 af = *(const f16x8*)&Axt[l16 * 264 + kk * 32 + q8];
      accP = __builtin_amdgcn_mfma_f32_16x16x32_f16(af, bfr[kk], accP, 0, 0, 0);
    }
    _Float16* xd = &Xl[((buf * 3 + g) * CH + quad * 4) * ND + dblk * 16 + l16];
#pragma unroll
    for (int r = 0; r < 4; ++r) xd[r * ND] = (_Float16)accP[r];
  };

  // ---- prologue: proj waves build chunk 0 ----
  if (!scanw) LOADX(0);
  __syncthreads();                     // k12 / LDS inits visible
  if (!scanw) STAGEX(0);
  __syncthreads();                     // Axt + sA[0..15] visible
  if (!scanw) {
    LOADB(0); GEMMG(0, 0);
    LOADB(1); GEMMG(1, 0);
    LOADB(2); GEMMG(2, 0);
  }

  const bool owner = scanw && (quad == 0);
  const int d = 16 * w + l16;          // scan: one d per owner lane
  float bbv[3] = {0.f, 0.f, 0.f};
  if (owner) { bbv[0] = b_r[d]; bbv[1] = b_z[d]; bbv[2] = b_h[d]; }
  __syncthreads();                     // Xl buf 0 visible

  // ---- scan per-step state ----
  const f32x4 kZ = (f32x4){0.f, 0.f, 0.f, 0.f};
  float a_c = 0.f;
  int ieff_c = 0;
  bool pf_c = true;
  float hp = 0.f;
  f32x4 accLa[3], accLb[3], accHa[3], accHb[3];
  if (scanw) {
    a_c = sA[0];
    ieff_c = sIeff[0];
#pragma unroll
    for (int g = 0; g < 3; ++g) {
      accLa[g] = kZ; accLb[g] = kZ; accHa[g] = kZ; accHb[g] = kZ;
    }
  }

  for (int t = 0; t < NL; ++t) {
    const int cur = (t >> 4) & 1;
    const int tin = t & 15;

    if (scanw) {
      const int par = t & 1;
      const float a = a_c;
      const float oma = 1.f - a;
      const int ieff = ieff_c;

      // ---- late-H path: hist row only became readable at this barrier ----
      if (!pf_c) {
        f16x8 g2 = *(const f16x8*)&hist[ieff * NH + q8];
        f16x8 g3 = *(const f16x8*)&hist[ieff * NH + 32 + q8];
#pragma unroll
        for (int g = 0; g < 3; ++g) {
          accHa[g] = __builtin_amdgcn_mfma_f32_16x16x32_f16(g2, bf[g][2], kZ, 0, 0, 0);
          accHb[g] = __builtin_amdgcn_mfma_f32_16x16x32_f16(g3, bf[g][3], kZ, 0, 0, 0);
        }
      }

      // ---- L-half (critical): raw h_{t-1}, independent MFMAs ----
      f16x8 h0 = *(const f16x8*)&hprev16[par][q8];
      f16x8 h1 = *(const f16x8*)&hprev16[par][32 + q8];
#pragma unroll
      for (int g = 0; g < 3; ++g) {
        accLa[g] = __builtin_amdgcn_mfma_f32_16x16x32_f16(h0, bf[g][0], kZ, 0, 0, 0);
        accLb[g] = __builtin_amdgcn_mfma_f32_16x16x32_f16(h1, bf[g][1], kZ, 0, 0, 0);
      }

      // ---- X + md for this step (owner lanes; straight Xl layout) ----
      float xv[3], md = 0.f;
      if (owner) {
#pragma unroll
        for (int g = 0; g < 3; ++g)
          xv[g] = (float)Xl[((cur * 3 + g) * CH + tin) * ND + d];
        if (w < 4) {
          md = a * hp;
        } else if (ieff == t) {
          md = oma * hp;
        } else {
          md = oma * (float)hist[ieff * NH + (d - NH)];
        }
      }

      // ---- prefetch step-(t+1) state ----
      const int tn = (t < NL - 1) ? t + 1 : t;
      float a_n = sA[tn];
      int ieff_n = sIeff[tn];
      bool pf_n = (ieff_n <= t);

      // ---- epilogue (owner lanes): a*L + (1-a)*H in f32 ----
      if (owner) {
        float mr = a * (accLa[0][0] + accLb[0][0]) + oma * (accHa[0][0] + accHb[0][0]);
        float mz = a * (accLa[1][0] + accLb[1][0]) + oma * (accHa[1][0] + accHb[1][0]);
        float mh = a * (accLa[2][0] + accLb[2][0]) + oma * (accHa[2][0] + accHb[2][0]);
        float er = __expf(-(xv[0] + bbv[0] + mr));
        float rr = __builtin_amdgcn_rcpf(1.f + er);
        float ez = __expf(-(xv[1] + bbv[1] + mz));
        float zz = __builtin_amdgcn_rcpf(1.f + ez);
        float e2 = __expf(2.f * (xv[2] + bbv[2] + rr * mh));
        float hh = (e2 - 1.f) * __builtin_amdgcn_rcpf(e2 + 1.f);
        float h = md + zz * (hh - md);   // (1-z)*m + z*hh
        hp = h;
        out[(rowb + t) * ND + d] = h;    // never drained per-step
        if (d < NH) hprev16[par ^ 1][d] = (_Float16)h;
        else        hist[(t + 1) * NH + (d - NH)] = (_Float16)h;
      }

      // ---- pre-issue next step's H half if its hist row is stable ----
      if (pf_n) {
        f16x8 g2 = *(const f16x8*)&hist[ieff_n * NH + q8];
        f16x8 g3 = *(const f16x8*)&hist[ieff_n * NH + 32 + q8];
#pragma unroll
        for (int g = 0; g < 3; ++g) {
          accHa[g] = __builtin_amdgcn_mfma_f32_16x16x32_f16(g2, bf[g][2], kZ, 0, 0, 0);
          accHb[g] = __builtin_amdgcn_mfma_f32_16x16x32_f16(g3, bf[g][3], kZ, 0, 0, 0);
        }
      }

      a_c = a_n; ieff_c = ieff_n; pf_c = pf_n;
    } else {
      // ---- projection waves: build chunk t0n into Xl[cur^1] ----
      const int t0n = (t & ~15) + 16;
      if (t0n < NL) {
        if (tin == 0)      LOADX(t0n);
        else if (tin == 2) STAGEX(t0n);
        else if (tin == 3) LOADB(0);
        else if (tin == 4) { GEMMG(0, cur ^ 1); LOADB(1); }
        else if (tin == 5) { GEMMG(1, cur ^ 1); LOADB(2); }
        else if (tin == 6) GEMMG(2, cur ^ 1);
      }
    }

    // ---- one barrier per step: LDS drain only ----
    BAR_LDS();
  }
}

// =====================================================================
extern "C" void kernel_launch(void* const* d_in, const int* in_sizes, int n_in,
                              void* d_out, int out_size, void* d_ws, size_t ws_size,
                              hipStream_t stream) {
  (void)in_sizes; (void)n_in; (void)out_size; (void)ws_size;
  const float* x    = (const float*)d_in[0];
  const int*   cor  = (const int*)d_in[1];
  const float* w_r  = (const float*)d_in[2];
  const float* b_r  = (const float*)d_in[3];
  const float* u_r  = (const float*)d_in[4];
  const float* w_z  = (const float*)d_in[5];
  const float* b_z  = (const float*)d_in[6];
  const float* u_z  = (const float*)d_in[7];
  const float* w_h  = (const float*)d_in[8];
  const float* b_h  = (const float*)d_in[9];
  const float* u_h  = (const float*)d_in[10];
  const float* k1k2 = (const float*)d_in[11];

  _Float16* wpk = (_Float16*)d_ws;   // 192 KB, L2-hot

  kwpack_kernel<<<dim3(24, 8), dim3(64), 0, stream>>>(w_r, w_z, w_h, wpk);
  kscan_kernel<<<dim3(NB), dim3(1024), 0, stream>>>(u_r, u_z, u_h, b_r, b_z,
                                                    b_h, cor, x, wpk, k1k2,
                                                    (float*)d_out);
}

// Round 6
// 726.079 us; speedup vs baseline: 1.2166x; 1.2166x over previous
//
#include <hip/hip_runtime.h>

typedef float f32x4 __attribute__((ext_vector_type(4)));
typedef _Float16 f16x8 __attribute__((ext_vector_type(8)));
typedef _Float16 f16x4 __attribute__((ext_vector_type(4)));
typedef _Float16 f16x2 __attribute__((ext_vector_type(2)));

#define NB 256
#define NL 256
#define NIN 256
#define ND 128
#define NH 64
#define CH 16                        // X-chunk (steps)

// raw barrier: LDS-only drain — global ops float across it
#define BAR_LDS() asm volatile("s_waitcnt lgkmcnt(0)\n\ts_barrier" ::: "memory")

// =====================================================================
// Kernel W: pack w_r|w_z|w_h (f32 [128][256]) into f16 fragment order.
// wpk[((nt*8+kc)*64+lane)*8+j] = w_gate[(nt&7)*16+(lane&15)]
//                                 [kc*32+(lane>>4)*8+j];  192 KB, L2-hot.
// =====================================================================
__global__ void kwpack_kernel(const float* __restrict__ w_r,
                              const float* __restrict__ w_z,
                              const float* __restrict__ w_h,
                              _Float16* __restrict__ wpk) {
  const int lane = threadIdx.x;        // 0..63
  const int nt = blockIdx.x;           // 0..23
  const int kc = blockIdx.y;           // 0..7
  const float* wg = (nt < 8) ? w_r : (nt < 16) ? w_z : w_h;
  const int col = (nt & 7) * 16 + (lane & 15);
  const int k0 = kc * 32 + (lane >> 4) * 8;
  const float4* p = (const float4*)(wg + (size_t)col * NIN + k0);
  float4 v0 = p[0], v1 = p[1];
  f16x8 f;
  f[0] = (_Float16)v0.x; f[1] = (_Float16)v0.y;
  f[2] = (_Float16)v0.z; f[3] = (_Float16)v0.w;
  f[4] = (_Float16)v1.x; f[5] = (_Float16)v1.y;
  f[6] = (_Float16)v1.z; f[7] = (_Float16)v1.w;
  *(f16x8*)&wpk[(((size_t)nt * 8 + kc) * 64 + lane) * 8] = f;
}

// =====================================================================
// Kernel C v13: v12 with the register budget FIXED.
//  R5 failure: __launch_bounds__(1024) -> compiler capped VGPR at 64
//  (targeting 8 waves/SIMD) -> per-step accumulators spilled to scratch
//  (WRITE_SIZE 860MB, MfmaUtil 5.8%). Fixes:
//   - __launch_bounds__(1024, 4): 4 waves/EU = 1 block/CU -> 128 VGPR cap.
//   - accL/accH chained (6 f32x4, was 12): -24 VGPR; R4 measured the
//     chain-split was only worth ~4us, the registers matter more here.
//  Scheduling/hazard structure byte-identical to v12 (passed).
// =====================================================================
__global__ __launch_bounds__(1024, 4) void kscan_kernel(
    const float* __restrict__ u_r, const float* __restrict__ u_z,
    const float* __restrict__ u_h, const float* __restrict__ b_r,
    const float* __restrict__ b_z, const float* __restrict__ b_h,
    const int* __restrict__ cor, const float* __restrict__ x,
    const _Float16* __restrict__ wpk, const float* __restrict__ k1k2,
    float* __restrict__ out) {
  const int b = blockIdx.x;
  const int tid = threadIdx.x;
  const int lane = tid & 63;
  const int w = tid >> 6;        // 0..15
  const bool scanw = (w < 8);    // waves 0..7 scan, 8..15 projection
  const int pw = w - 8;          // proj wave id 0..7
  const int quad = lane >> 4;
  const int l16 = lane & 15;
  const int q8 = quad * 8;

  __shared__ __align__(16) _Float16 hist[(NL + 1) * NH];   // 32896 B
  __shared__ __align__(16) _Float16 Xl[2 * 3 * CH * ND];   // 24576 B
  __shared__ __align__(16) _Float16 Axt[16 * 264];         // 8448 B (pad 264)
  __shared__ __align__(16) _Float16 hprev16[2][NH];        // 256 B (parity)
  __shared__ float sA[NL];                                 // 1024 B
  __shared__ int sIeff[NL];                                // 1024 B
  __shared__ float k12[NIN];                               // 1024 B

  const size_t rowb = (size_t)b * NL;

  // ---- scan waves: U fragments; n = 16w+l16, k = kk*32+q8+j ----
  f16x8 bf[3][4];
  if (scanw) {
#pragma unroll
    for (int g = 0; g < 3; ++g) {
      const float* ug = (g == 0) ? u_r : (g == 1) ? u_z : u_h;
      const float* base = ug + (size_t)(16 * w + l16) * ND;
#pragma unroll
      for (int kk = 0; kk < 4; ++kk) {
        const float4* p = (const float4*)(base + kk * 32 + q8);
        float4 v0 = p[0], v1 = p[1];
        f16x8 f;
        f[0] = (_Float16)v0.x; f[1] = (_Float16)v0.y;
        f[2] = (_Float16)v0.z; f[3] = (_Float16)v0.w;
        f[4] = (_Float16)v1.x; f[5] = (_Float16)v1.y;
        f[6] = (_Float16)v1.z; f[7] = (_Float16)v1.w;
        bf[g][kk] = f;
      }
    }
  }

  if (tid < NH) { hprev16[0][tid] = (_Float16)0.f; hist[tid] = (_Float16)0.f; }
  if (tid < NL) {
    const int c = cor[rowb + tid];
    sIeff[tid] = (c == 0) ? tid : c;
  }
  if (tid < NIN) k12[tid] = k1k2[tid] - k1k2[NIN + tid];

  // ---- proj-wave machinery ----
  const int prow0 = 2 * pw;            // chunk-local rows this wave stages
  float4 xrA0, xrB0;                   // staged x rows (4 f32/lane each)
  f16x8 bfr[8];                        // W-frags for one n-tile

  auto LOADX = [&](int t0) {
    const float4* pa = (const float4*)(x + (rowb + t0 + prow0) * NIN + lane * 4);
    const float4* pb = (const float4*)(x + (rowb + t0 + prow0 + 1) * NIN + lane * 4);
    xrA0 = pa[0];
    xrB0 = pb[0];
  };
  auto STAGEX = [&](int t0) {
    f16x4 ha, hb;
    ha[0] = (_Float16)xrA0.x; ha[1] = (_Float16)xrA0.y;
    ha[2] = (_Float16)xrA0.z; ha[3] = (_Float16)xrA0.w;
    hb[0] = (_Float16)xrB0.x; hb[1] = (_Float16)xrB0.y;
    hb[2] = (_Float16)xrB0.z; hb[3] = (_Float16)xrB0.w;
    *(f16x4*)&Axt[prow0 * 264 + lane * 4] = ha;
    *(f16x4*)&Axt[(prow0 + 1) * 264 + lane * 4] = hb;
    const float4 kk = *(const float4*)&k12[lane * 4];
    float pa = xrA0.x * kk.x + xrA0.y * kk.y + xrA0.z * kk.z + xrA0.w * kk.w;
    float pb = xrB0.x * kk.x + xrB0.y * kk.y + xrB0.z * kk.z + xrB0.w * kk.w;
#pragma unroll
    for (int s = 1; s < 64; s <<= 1) {
      pa += __shfl_xor(pa, s);
      pb += __shfl_xor(pb, s);
    }
    if (lane == 0) {
      sA[t0 + prow0] = 1.f / (1.f + __expf(-pa));
      sA[t0 + prow0 + 1] = 1.f / (1.f + __expf(-pb));
    }
  };
  auto LOADB = [&](int i) {
    const int nt = pw * 3 + i;
#pragma unroll
    for (int kk = 0; kk < 8; ++kk)
      bfr[kk] = *(const f16x8*)&wpk[(((size_t)nt * 8 + kk) * 64 + lane) * 8];
  };
  auto GEMMG = [&](int i, int buf) {
    const int nt = pw * 3 + i;
    const int g = nt >> 3;
    const int dblk = nt & 7;
    f32x4 accP = (f32x4){0.f, 0.f, 0.f, 0.f};
#pragma unroll
    for (int kk = 0; kk < 8; ++kk) {
      f16x8 af = *(const f16x8*)&Axt[l16 * 264 + kk * 32 + q8];
      accP = __builtin_amdgcn_mfma_f32_16x16x32_f16(af, bfr[kk], accP, 0, 0, 0);
    }
    _Float16* xd = &Xl[((buf * 3 + g) * CH + quad * 4) * ND + dblk * 16 + l16];
#pragma unroll
    for (int r = 0; r < 4; ++r) xd[r * ND] = (_Float16)accP[r];
  };

  // ---- prologue: proj waves build chunk 0 ----
  if (!scanw) LOADX(0);
  __syncthreads();                     // k12 / LDS inits visible
  if (!scanw) STAGEX(0);
  __syncthreads();                     // Axt + sA[0..15] visible
  if (!scanw) {
    LOADB(0); GEMMG(0, 0);
    LOADB(1); GEMMG(1, 0);
    LOADB(2); GEMMG(2, 0);
  }

  const bool owner = scanw && (quad == 0);
  const int d = 16 * w + l16;          // scan: one d per owner lane
  float bbv[3] = {0.f, 0.f, 0.f};
  if (owner) { bbv[0] = b_r[d]; bbv[1] = b_z[d]; bbv[2] = b_h[d]; }
  __syncthreads();                     // Xl buf 0 visible

  // ---- scan per-step state ----
  const f32x4 kZ = (f32x4){0.f, 0.f, 0.f, 0.f};
  float a_c = 0.f;
  int ieff_c = 0;
  bool pf_c = true;
  float hp = 0.f;
  f32x4 accL[3], accH[3];
  if (scanw) {
    a_c = sA[0];
    ieff_c = sIeff[0];
#pragma unroll
    for (int g = 0; g < 3; ++g) { accL[g] = kZ; accH[g] = kZ; }
  }

  for (int t = 0; t < NL; ++t) {
    const int cur = (t >> 4) & 1;
    const int tin = t & 15;

    if (scanw) {
      const int par = t & 1;
      const float a = a_c;
      const float oma = 1.f - a;
      const int ieff = ieff_c;

      // ---- late-H path: hist row only became readable at this barrier ----
      if (!pf_c) {
        f16x8 g2 = *(const f16x8*)&hist[ieff * NH + q8];
        f16x8 g3 = *(const f16x8*)&hist[ieff * NH + 32 + q8];
#pragma unroll
        for (int g = 0; g < 3; ++g) {
          accH[g] = __builtin_amdgcn_mfma_f32_16x16x32_f16(g2, bf[g][2], kZ, 0, 0, 0);
          accH[g] = __builtin_amdgcn_mfma_f32_16x16x32_f16(g3, bf[g][3], accH[g], 0, 0, 0);
        }
      }

      // ---- L-half (critical): raw h_{t-1} ----
      f16x8 h0 = *(const f16x8*)&hprev16[par][q8];
      f16x8 h1 = *(const f16x8*)&hprev16[par][32 + q8];
#pragma unroll
      for (int g = 0; g < 3; ++g) {
        accL[g] = __builtin_amdgcn_mfma_f32_16x16x32_f16(h0, bf[g][0], kZ, 0, 0, 0);
        accL[g] = __builtin_amdgcn_mfma_f32_16x16x32_f16(h1, bf[g][1], accL[g], 0, 0, 0);
      }

      // ---- X + md for this step (owner lanes; straight Xl layout) ----
      float xv[3], md = 0.f;
      if (owner) {
#pragma unroll
        for (int g = 0; g < 3; ++g)
          xv[g] = (float)Xl[((cur * 3 + g) * CH + tin) * ND + d];
        if (w < 4) {
          md = a * hp;
        } else if (ieff == t) {
          md = oma * hp;
        } else {
          md = oma * (float)hist[ieff * NH + (d - NH)];
        }
      }

      // ---- prefetch step-(t+1) state ----
      const int tn = (t < NL - 1) ? t + 1 : t;
      float a_n = sA[tn];
      int ieff_n = sIeff[tn];
      bool pf_n = (ieff_n <= t);

      // ---- epilogue (owner lanes): a*L + (1-a)*H in f32 ----
      if (owner) {
        float mr = a * accL[0][0] + oma * accH[0][0];
        float mz = a * accL[1][0] + oma * accH[1][0];
        float mh = a * accL[2][0] + oma * accH[2][0];
        float er = __expf(-(xv[0] + bbv[0] + mr));
        float rr = __builtin_amdgcn_rcpf(1.f + er);
        float ez = __expf(-(xv[1] + bbv[1] + mz));
        float zz = __builtin_amdgcn_rcpf(1.f + ez);
        float e2 = __expf(2.f * (xv[2] + bbv[2] + rr * mh));
        float hh = (e2 - 1.f) * __builtin_amdgcn_rcpf(e2 + 1.f);
        float h = md + zz * (hh - md);   // (1-z)*m + z*hh
        hp = h;
        out[(rowb + t) * ND + d] = h;    // never drained per-step
        if (d < NH) hprev16[par ^ 1][d] = (_Float16)h;
        else        hist[(t + 1) * NH + (d - NH)] = (_Float16)h;
      }

      // ---- pre-issue next step's H half if its hist row is stable ----
      if (pf_n) {
        f16x8 g2 = *(const f16x8*)&hist[ieff_n * NH + q8];
        f16x8 g3 = *(const f16x8*)&hist[ieff_n * NH + 32 + q8];
#pragma unroll
        for (int g = 0; g < 3; ++g) {
          accH[g] = __builtin_amdgcn_mfma_f32_16x16x32_f16(g2, bf[g][2], kZ, 0, 0, 0);
          accH[g] = __builtin_amdgcn_mfma_f32_16x16x32_f16(g3, bf[g][3], accH[g], 0, 0, 0);
        }
      }

      a_c = a_n; ieff_c = ieff_n; pf_c = pf_n;
    } else {
      // ---- projection waves: build chunk t0n into Xl[cur^1] ----
      const int t0n = (t & ~15) + 16;
      if (t0n < NL) {
        if (tin == 0)      LOADX(t0n);
        else if (tin == 2) STAGEX(t0n);
        else if (tin == 3) LOADB(0);
        else if (tin == 4) { GEMMG(0, cur ^ 1); LOADB(1); }
        else if (tin == 5) { GEMMG(1, cur ^ 1); LOADB(2); }
        else if (tin == 6) GEMMG(2, cur ^ 1);
      }
    }

    // ---- one barrier per step: LDS drain only ----
    BAR_LDS();
  }
}

// =====================================================================
extern "C" void kernel_launch(void* const* d_in, const int* in_sizes, int n_in,
                              void* d_out, int out_size, void* d_ws, size_t ws_size,
                              hipStream_t stream) {
  (void)in_sizes; (void)n_in; (void)out_size; (void)ws_size;
  const float* x    = (const float*)d_in[0];
  const int*   cor  = (const int*)d_in[1];
  const float* w_r  = (const float*)d_in[2];
  const float* b_r  = (const float*)d_in[3];
  const float* u_r  = (const float*)d_in[4];
  const float* w_z  = (const float*)d_in[5];
  const float* b_z  = (const float*)d_in[6];
  const float* u_z  = (const float*)d_in[7];
  const float* w_h  = (const float*)d_in[8];
  const float* b_h  = (const float*)d_in[9];
  const float* u_h  = (const float*)d_in[10];
  const float* k1k2 = (const float*)d_in[11];

  _Float16* wpk = (_Float16*)d_ws;   // 192 KB, L2-hot

  kwpack_kernel<<<dim3(24, 8), dim3(64), 0, stream>>>(w_r, w_z, w_h, wpk);
  kscan_kernel<<<dim3(NB), dim3(1024), 0, stream>>>(u_r, u_z, u_h, b_r, b_z,
                                                    b_h, cor, x, wpk, k1k2,
                                                    (float*)d_out);
}

// Round 7
// 681.700 us; speedup vs baseline: 1.2958x; 1.0651x over previous
//
#include <hip/hip_runtime.h>

typedef float f32x4 __attribute__((ext_vector_type(4)));
typedef _Float16 f16x8 __attribute__((ext_vector_type(8)));
typedef _Float16 f16x4 __attribute__((ext_vector_type(4)));
typedef _Float16 f16x2 __attribute__((ext_vector_type(2)));

#define NB 256
#define NL 256
#define NIN 256
#define ND 128
#define NH 64
#define CH 16                        // X-chunk (steps)

// raw barrier: LDS-only drain — global ops float across it
#define BAR_LDS() asm volatile("s_waitcnt lgkmcnt(0)\n\ts_barrier" ::: "memory")

// =====================================================================
// Kernel W: pack w_r|w_z|w_h (f32 [128][256]) into f16 fragment order.
// wpk[((nt*8+kc)*64+lane)*8+j] = w_gate[(nt&7)*16+(lane&15)]
//                                 [kc*32+(lane>>4)*8+j];  192 KB, L2-hot.
// =====================================================================
__global__ void kwpack_kernel(const float* __restrict__ w_r,
                              const float* __restrict__ w_z,
                              const float* __restrict__ w_h,
                              _Float16* __restrict__ wpk) {
  const int lane = threadIdx.x;        // 0..63
  const int nt = blockIdx.x;           // 0..23
  const int kc = blockIdx.y;           // 0..7
  const float* wg = (nt < 8) ? w_r : (nt < 16) ? w_z : w_h;
  const int col = (nt & 7) * 16 + (lane & 15);
  const int k0 = kc * 32 + (lane >> 4) * 8;
  const float4* p = (const float4*)(wg + (size_t)col * NIN + k0);
  float4 v0 = p[0], v1 = p[1];
  f16x8 f;
  f[0] = (_Float16)v0.x; f[1] = (_Float16)v0.y;
  f[2] = (_Float16)v0.z; f[3] = (_Float16)v0.w;
  f[4] = (_Float16)v1.x; f[5] = (_Float16)v1.y;
  f[6] = (_Float16)v1.z; f[7] = (_Float16)v1.w;
  *(f16x8*)&wpk[(((size_t)nt * 8 + kc) * 64 + lane) * 8] = f;
}

// =====================================================================
// Kernel C v14: v13 with the VGPR cap ACTUALLY raised.
//  R5/R6 mechanism: backend sets the VGPR budget from LDS-permitted max
//  occupancy. 68KB LDS -> 2 blocks/CU "fit" -> 8 waves/EU target ->
//  64-VGPR cap -> spills (static need ~110: scan bf[48] + proj bfr[32]
//  both loop-live). But grid == 256 == #CUs, so a 2nd co-resident block
//  never exists. FIX: pad LDS past 80KB (hist +14336B) so only 1
//  block/CU fits -> 4 waves/EU target -> 128-VGPR cap. Zero runtime
//  cost (occupancy was already 1 block/CU). Everything else identical
//  to v13 (functionally verified twice).
// =====================================================================
#define HIST_PAD 7168                 // f16 elems: pushes LDS > 80KB

__global__ __launch_bounds__(1024, 4) void kscan_kernel(
    const float* __restrict__ u_r, const float* __restrict__ u_z,
    const float* __restrict__ u_h, const float* __restrict__ b_r,
    const float* __restrict__ b_z, const float* __restrict__ b_h,
    const int* __restrict__ cor, const float* __restrict__ x,
    const _Float16* __restrict__ wpk, const float* __restrict__ k1k2,
    float* __restrict__ out) {
  const int b = blockIdx.x;
  const int tid = threadIdx.x;
  const int lane = tid & 63;
  const int w = tid >> 6;        // 0..15
  const bool scanw = (w < 8);    // waves 0..7 scan, 8..15 projection
  const int pw = w - 8;          // proj wave id 0..7
  const int quad = lane >> 4;
  const int l16 = lane & 15;
  const int q8 = quad * 8;

  __shared__ __align__(16) _Float16 hist[(NL + 1) * NH + HIST_PAD]; // 47232 B
  __shared__ __align__(16) _Float16 Xl[2 * 3 * CH * ND];   // 24576 B
  __shared__ __align__(16) _Float16 Axt[16 * 264];         // 8448 B (pad 264)
  __shared__ __align__(16) _Float16 hprev16[2][NH];        // 256 B (parity)
  __shared__ float sA[NL];                                 // 1024 B
  __shared__ int sIeff[NL];                                // 1024 B
  __shared__ float k12[NIN];                               // 1024 B

  const size_t rowb = (size_t)b * NL;

  // ---- scan waves: U fragments; n = 16w+l16, k = kk*32+q8+j ----
  f16x8 bf[3][4];
  if (scanw) {
#pragma unroll
    for (int g = 0; g < 3; ++g) {
      const float* ug = (g == 0) ? u_r : (g == 1) ? u_z : u_h;
      const float* base = ug + (size_t)(16 * w + l16) * ND;
#pragma unroll
      for (int kk = 0; kk < 4; ++kk) {
        const float4* p = (const float4*)(base + kk * 32 + q8);
        float4 v0 = p[0], v1 = p[1];
        f16x8 f;
        f[0] = (_Float16)v0.x; f[1] = (_Float16)v0.y;
        f[2] = (_Float16)v0.z; f[3] = (_Float16)v0.w;
        f[4] = (_Float16)v1.x; f[5] = (_Float16)v1.y;
        f[6] = (_Float16)v1.z; f[7] = (_Float16)v1.w;
        bf[g][kk] = f;
      }
    }
  }

  if (tid < NH) { hprev16[0][tid] = (_Float16)0.f; hist[tid] = (_Float16)0.f; }
  if (tid < NL) {
    const int c = cor[rowb + tid];
    sIeff[tid] = (c == 0) ? tid : c;
  }
  if (tid < NIN) k12[tid] = k1k2[tid] - k1k2[NIN + tid];

  // ---- proj-wave machinery ----
  const int prow0 = 2 * pw;            // chunk-local rows this wave stages
  float4 xrA0, xrB0;                   // staged x rows (4 f32/lane each)
  f16x8 bfr[8];                        // W-frags for one n-tile

  auto LOADX = [&](int t0) {
    const float4* pa = (const float4*)(x + (rowb + t0 + prow0) * NIN + lane * 4);
    const float4* pb = (const float4*)(x + (rowb + t0 + prow0 + 1) * NIN + lane * 4);
    xrA0 = pa[0];
    xrB0 = pb[0];
  };
  auto STAGEX = [&](int t0) {
    f16x4 ha, hb;
    ha[0] = (_Float16)xrA0.x; ha[1] = (_Float16)xrA0.y;
    ha[2] = (_Float16)xrA0.z; ha[3] = (_Float16)xrA0.w;
    hb[0] = (_Float16)xrB0.x; hb[1] = (_Float16)xrB0.y;
    hb[2] = (_Float16)xrB0.z; hb[3] = (_Float16)xrB0.w;
    *(f16x4*)&Axt[prow0 * 264 + lane * 4] = ha;
    *(f16x4*)&Axt[(prow0 + 1) * 264 + lane * 4] = hb;
    const float4 kk = *(const float4*)&k12[lane * 4];
    float pa = xrA0.x * kk.x + xrA0.y * kk.y + xrA0.z * kk.z + xrA0.w * kk.w;
    float pb = xrB0.x * kk.x + xrB0.y * kk.y + xrB0.z * kk.z + xrB0.w * kk.w;
#pragma unroll
    for (int s = 1; s < 64; s <<= 1) {
      pa += __shfl_xor(pa, s);
      pb += __shfl_xor(pb, s);
    }
    if (lane == 0) {
      sA[t0 + prow0] = 1.f / (1.f + __expf(-pa));
      sA[t0 + prow0 + 1] = 1.f / (1.f + __expf(-pb));
    }
  };
  auto LOADB = [&](int i) {
    const int nt = pw * 3 + i;
#pragma unroll
    for (int kk = 0; kk < 8; ++kk)
      bfr[kk] = *(const f16x8*)&wpk[(((size_t)nt * 8 + kk) * 64 + lane) * 8];
  };
  auto GEMMG = [&](int i, int buf) {
    const int nt = pw * 3 + i;
    const int g = nt >> 3;
    const int dblk = nt & 7;
    f32x4 accP = (f32x4){0.f, 0.f, 0.f, 0.f};
#pragma unroll
    for (int kk = 0; kk < 8; ++kk) {
      f16x8 af = *(const f16x8*)&Axt[l16 * 264 + kk * 32 + q8];
      accP = __builtin_amdgcn_mfma_f32_16x16x32_f16(af, bfr[kk], accP, 0, 0, 0);
    }
    _Float16* xd = &Xl[((buf * 3 + g) * CH + quad * 4) * ND + dblk * 16 + l16];
#pragma unroll
    for (int r = 0; r < 4; ++r) xd[r * ND] = (_Float16)accP[r];
  };

  // ---- prologue: proj waves build chunk 0 ----
  if (!scanw) LOADX(0);
  __syncthreads();                     // k12 / LDS inits visible
  if (!scanw) STAGEX(0);
  __syncthreads();                     // Axt + sA[0..15] visible
  if (!scanw) {
    LOADB(0); GEMMG(0, 0);
    LOADB(1); GEMMG(1, 0);
    LOADB(2); GEMMG(2, 0);
  }

  const bool owner = scanw && (quad == 0);
  const int d = 16 * w + l16;          // scan: one d per owner lane
  float bbv[3] = {0.f, 0.f, 0.f};
  if (owner) { bbv[0] = b_r[d]; bbv[1] = b_z[d]; bbv[2] = b_h[d]; }
  __syncthreads();                     // Xl buf 0 visible

  // ---- scan per-step state ----
  const f32x4 kZ = (f32x4){0.f, 0.f, 0.f, 0.f};
  float a_c = 0.f;
  int ieff_c = 0;
  bool pf_c = true;
  float hp = 0.f;
  f32x4 accL[3], accH[3];
  if (scanw) {
    a_c = sA[0];
    ieff_c = sIeff[0];
#pragma unroll
    for (int g = 0; g < 3; ++g) { accL[g] = kZ; accH[g] = kZ; }
  }

  for (int t = 0; t < NL; ++t) {
    const int cur = (t >> 4) & 1;
    const int tin = t & 15;

    if (scanw) {
      const int par = t & 1;
      const float a = a_c;
      const float oma = 1.f - a;
      const int ieff = ieff_c;

      // ---- late-H path: hist row only became readable at this barrier ----
      if (!pf_c) {
        f16x8 g2 = *(const f16x8*)&hist[ieff * NH + q8];
        f16x8 g3 = *(const f16x8*)&hist[ieff * NH + 32 + q8];
#pragma unroll
        for (int g = 0; g < 3; ++g) {
          accH[g] = __builtin_amdgcn_mfma_f32_16x16x32_f16(g2, bf[g][2], kZ, 0, 0, 0);
          accH[g] = __builtin_amdgcn_mfma_f32_16x16x32_f16(g3, bf[g][3], accH[g], 0, 0, 0);
        }
      }

      // ---- L-half (critical): raw h_{t-1} ----
      f16x8 h0 = *(const f16x8*)&hprev16[par][q8];
      f16x8 h1 = *(const f16x8*)&hprev16[par][32 + q8];
#pragma unroll
      for (int g = 0; g < 3; ++g) {
        accL[g] = __builtin_amdgcn_mfma_f32_16x16x32_f16(h0, bf[g][0], kZ, 0, 0, 0);
        accL[g] = __builtin_amdgcn_mfma_f32_16x16x32_f16(h1, bf[g][1], accL[g], 0, 0, 0);
      }

      // ---- X + md for this step (owner lanes; straight Xl layout) ----
      float xv[3], md = 0.f;
      if (owner) {
#pragma unroll
        for (int g = 0; g < 3; ++g)
          xv[g] = (float)Xl[((cur * 3 + g) * CH + tin) * ND + d];
        if (w < 4) {
          md = a * hp;
        } else if (ieff == t) {
          md = oma * hp;
        } else {
          md = oma * (float)hist[ieff * NH + (d - NH)];
        }
      }

      // ---- prefetch step-(t+1) state ----
      const int tn = (t < NL - 1) ? t + 1 : t;
      float a_n = sA[tn];
      int ieff_n = sIeff[tn];
      bool pf_n = (ieff_n <= t);

      // ---- epilogue (owner lanes): a*L + (1-a)*H in f32 ----
      if (owner) {
        float mr = a * accL[0][0] + oma * accH[0][0];
        float mz = a * accL[1][0] + oma * accH[1][0];
        float mh = a * accL[2][0] + oma * accH[2][0];
        float er = __expf(-(xv[0] + bbv[0] + mr));
        float rr = __builtin_amdgcn_rcpf(1.f + er);
        float ez = __expf(-(xv[1] + bbv[1] + mz));
        float zz = __builtin_amdgcn_rcpf(1.f + ez);
        float e2 = __expf(2.f * (xv[2] + bbv[2] + rr * mh));
        float hh = (e2 - 1.f) * __builtin_amdgcn_rcpf(e2 + 1.f);
        float h = md + zz * (hh - md);   // (1-z)*m + z*hh
        hp = h;
        out[(rowb + t) * ND + d] = h;    // never drained per-step
        if (d < NH) hprev16[par ^ 1][d] = (_Float16)h;
        else        hist[(t + 1) * NH + (d - NH)] = (_Float16)h;
      }

      // ---- pre-issue next step's H half if its hist row is stable ----
      if (pf_n) {
        f16x8 g2 = *(const f16x8*)&hist[ieff_n * NH + q8];
        f16x8 g3 = *(const f16x8*)&hist[ieff_n * NH + 32 + q8];
#pragma unroll
        for (int g = 0; g < 3; ++g) {
          accH[g] = __builtin_amdgcn_mfma_f32_16x16x32_f16(g2, bf[g][2], kZ, 0, 0, 0);
          accH[g] = __builtin_amdgcn_mfma_f32_16x16x32_f16(g3, bf[g][3], accH[g], 0, 0, 0);
        }
      }

      a_c = a_n; ieff_c = ieff_n; pf_c = pf_n;
    } else {
      // ---- projection waves: build chunk t0n into Xl[cur^1] ----
      const int t0n = (t & ~15) + 16;
      if (t0n < NL) {
        if (tin == 0)      LOADX(t0n);
        else if (tin == 2) STAGEX(t0n);
        else if (tin == 3) LOADB(0);
        else if (tin == 4) { GEMMG(0, cur ^ 1); LOADB(1); }
        else if (tin == 5) { GEMMG(1, cur ^ 1); LOADB(2); }
        else if (tin == 6) GEMMG(2, cur ^ 1);
      }
    }

    // ---- one barrier per step: LDS drain only ----
    BAR_LDS();
  }
}

// =====================================================================
extern "C" void kernel_launch(void* const* d_in, const int* in_sizes, int n_in,
                              void* d_out, int out_size, void* d_ws, size_t ws_size,
                              hipStream_t stream) {
  (void)in_sizes; (void)n_in; (void)out_size; (void)ws_size;
  const float* x    = (const float*)d_in[0];
  const int*   cor  = (const int*)d_in[1];
  const float* w_r  = (const float*)d_in[2];
  const float* b_r  = (const float*)d_in[3];
  const float* u_r  = (const float*)d_in[4];
  const float* w_z  = (const float*)d_in[5];
  const float* b_z  = (const float*)d_in[6];
  const float* u_z  = (const float*)d_in[7];
  const float* w_h  = (const float*)d_in[8];
  const float* b_h  = (const float*)d_in[9];
  const float* u_h  = (const float*)d_in[10];
  const float* k1k2 = (const float*)d_in[11];

  _Float16* wpk = (_Float16*)d_ws;   // 192 KB, L2-hot

  kwpack_kernel<<<dim3(24, 8), dim3(64), 0, stream>>>(w_r, w_z, w_h, wpk);
  kscan_kernel<<<dim3(NB), dim3(1024), 0, stream>>>(u_r, u_z, u_h, b_r, b_z,
                                                    b_h, cor, x, wpk, k1k2,
                                                    (float*)d_out);
}